// Round 4
// baseline (282.496 us; speedup 1.0000x reference)
//
#include <hip/hip_runtime.h>
#include <hip/hip_bf16.h>
#include <stdint.h>

// Problem constants
#define EDIM 1024
#define NH   16
#define HD   64
#define BB   4
#define SS   2048
#define MROWS (BB*SS)   // 8192

typedef __bf16 bf16x8 __attribute__((ext_vector_type(8)));
typedef __bf16 bf16x4 __attribute__((ext_vector_type(4)));
typedef float  f32x4  __attribute__((ext_vector_type(4)));

__device__ __forceinline__ void async16(const void* g, void* lds) {
    __builtin_amdgcn_global_load_lds((__attribute__((address_space(1))) void*)(g),
                                     (__attribute__((address_space(3))) void*)(lds),
                                     16, 0, 0);
}

__device__ __forceinline__ f32x4 mfma16(bf16x8 a, bf16x8 b, f32x4 c) {
    return __builtin_amdgcn_mfma_f32_16x16x32_bf16(a, b, c, 0, 0, 0);
}

// ---------------- fp32 -> bf16 conversion (vectorized) ----------------
__global__ __launch_bounds__(256) void cvt_kernel(const float* __restrict__ s,
                                                  __bf16* __restrict__ d, int n) {
    int i = (blockIdx.x * 256 + threadIdx.x) * 4;
    if (i < n) {
        float4 v = *reinterpret_cast<const float4*>(s + i);
        bf16x4 o;
        o.x = (__bf16)v.x; o.y = (__bf16)v.y; o.z = (__bf16)v.z; o.w = (__bf16)v.w;
        *reinterpret_cast<bf16x4*>(d + i) = o;
    }
}

// ---------------- GEMM: C[m][n] = sum_k A[m][k]*W[n][k] + bias[n] ----------------
__global__ __launch_bounds__(256) void gemm_bt(const __bf16* __restrict__ A,
                                               const __bf16* __restrict__ W,
                                               const float* __restrict__ bias,
                                               void* __restrict__ dst, int mode) {
    __shared__ char As[128 * 64];  // 128 rows x 32 bf16 (64B), XOR-swizzled slots
    __shared__ char Bs[128 * 64];

    const int tid = threadIdx.x;
    const int w = tid >> 6, l = tid & 63;
    const int bm = blockIdx.x * 128, bn = blockIdx.y * 128;
    const int wm = (w >> 1) * 64, wn = (w & 1) * 64;

    f32x4 acc[4][4] = {};

    const int lrow = l & 15;
    const int lslot = l >> 4;

    for (int kt = 0; kt < EDIM / 32; ++kt) {
        const int k0 = kt * 32;
        #pragma unroll
        for (int i = 0; i < 2; ++i) {
            int c = i * 256 + tid;
            int row = c >> 2, cb = c & 3;
            int gk = k0 + ((cb ^ (row & 3)) << 3);   // pre-swizzled global source
            async16(A + (size_t)(bm + row) * EDIM + gk, As + (i * 256 + w * 64) * 16);
            async16(W + (size_t)(bn + row) * EDIM + gk, Bs + (i * 256 + w * 64) * 16);
        }
        __syncthreads();

        bf16x8 af[4], bfr[4];
        #pragma unroll
        for (int mf = 0; mf < 4; ++mf) {
            int row = wm + mf * 16 + lrow;
            af[mf] = *reinterpret_cast<const bf16x8*>(As + row * 64 + ((lslot ^ (row & 3)) << 4));
        }
        #pragma unroll
        for (int nf = 0; nf < 4; ++nf) {
            int row = wn + nf * 16 + lrow;
            bfr[nf] = *reinterpret_cast<const bf16x8*>(Bs + row * 64 + ((lslot ^ (row & 3)) << 4));
        }
        #pragma unroll
        for (int mf = 0; mf < 4; ++mf)
            #pragma unroll
            for (int nf = 0; nf < 4; ++nf)
                acc[mf][nf] = mfma16(af[mf], bfr[nf], acc[mf][nf]);
        __syncthreads();
    }

    #pragma unroll
    for (int nf = 0; nf < 4; ++nf) {
        int ng = bn + wn + nf * 16 + lrow;
        float bv = bias[ng];
        #pragma unroll
        for (int mf = 0; mf < 4; ++mf) {
            #pragma unroll
            for (int r = 0; r < 4; ++r) {
                int mg = bm + wm + mf * 16 + (l >> 4) * 4 + r;
                float v = acc[mf][nf][r] + bv;
                if (mode == 3) {
                    ((float*)dst)[(size_t)mg * EDIM + ng] = v;
                } else {
                    int b = mg >> 11, s = mg & 2047;
                    int h = ng >> 6, d = ng & 63;
                    size_t idx;
                    if (mode == 2) idx = ((size_t)(b * NH + h) * HD + d) * SS + s;
                    else           idx = ((size_t)(b * NH + h) * SS + s) * HD + d;
                    ((__bf16*)dst)[idx] = (__bf16)v;
                }
            }
        }
    }
}

// ---------------- Flash attention (causal, pair-balanced) ----------------
// Q,K: [B,H,S,D] bf16.  Vt: [B,H,D,S] bf16.  Oa: [B,S,H*D] bf16.
// grid.y = 16 pairs; block p processes q-tiles {p, 31-p}: 33 K-tiles each.
#define SCL2E 0.18033688f   /* 0.125 * log2(e) */

__global__ __launch_bounds__(256) void attn_kernel(const __bf16* __restrict__ Q,
                                                   const __bf16* __restrict__ K,
                                                   const __bf16* __restrict__ Vt,
                                                   __bf16* __restrict__ Oa) {
    __shared__ char ks[64 * 128];      // K tile: row t (64 d * 2B), swizzled
    __shared__ char vs[64 * 128];      // Vt tile: row d (64 t * 2B), swizzled
    __shared__ char Pl[4][16 * 128];   // per-wave P: row q (64 t * 2B), swizzled

    const int bh = blockIdx.x;   // 0..63
    const int pr = blockIdx.y;   // 0..15
    const int tid = threadIdx.x;
    const int w = tid >> 6, l = tid & 63;
    const int lrow = l & 15, lslot = l >> 4;

    const __bf16* Qp = Q + (size_t)bh * (SS * HD);
    const __bf16* Kp = K + (size_t)bh * (SS * HD);
    const __bf16* Vp = Vt + (size_t)bh * (HD * SS);

    // staging lane constants (chunk c = i*256+tid, i in {0,1})
    const int rowS0 = tid >> 3,          cb0 = tid & 7;
    const int rowS1 = (256 + tid) >> 3,  cb1 = tid & 7;  // (256+tid)&7 == tid&7
    const int gs0 = (cb0 ^ (rowS0 & 7)) << 3;
    const int gs1 = (cb1 ^ (rowS1 & 7)) << 3;
    char* ldst0 = (char*)ks + (w * 64) * 16;
    char* ldst1 = (char*)ks + (256 + w * 64) * 16;
    char* ldsv0 = (char*)vs + (w * 64) * 16;
    char* ldsv1 = (char*)vs + (256 + w * 64) * 16;

    const int b = bh >> 4, h = bh & 15;

    #pragma unroll 1
    for (int which = 0; which < 2; ++which) {
        const int qt = which ? (31 - pr) : pr;

        // Q fragments (A operand)
        const int qrow = qt * 64 + w * 16 + lrow;
        bf16x8 qf[2];
        qf[0] = *reinterpret_cast<const bf16x8*>(Qp + (size_t)qrow * HD + lslot * 8);
        qf[1] = *reinterpret_cast<const bf16x8*>(Qp + (size_t)qrow * HD + 32 + lslot * 8);

        f32x4 oacc[4] = {};
        float mrow[4] = {-1e30f, -1e30f, -1e30f, -1e30f};
        float lsum[4] = {0.f, 0.f, 0.f, 0.f};

        const int qg0 = qt * 64 + w * 16 + (l >> 4) * 4;
        const int ntiles = qt + 1;

        // strength-reduced global source pointers
        const __bf16* kp0 = Kp + (size_t)rowS0 * HD + gs0;
        const __bf16* kp1 = Kp + (size_t)rowS1 * HD + gs1;
        const __bf16* vp0 = Vp + (size_t)rowS0 * SS + gs0;
        const __bf16* vp1 = Vp + (size_t)rowS1 * SS + gs1;

        for (int kt = 0; kt < ntiles; ++kt) {
            const int kv0 = kt * 64;
            async16(kp0, ldst0);
            async16(kp1, ldst1);
            async16(vp0, ldsv0);
            async16(vp1, ldsv1);
            kp0 += 64 * HD; kp1 += 64 * HD; vp0 += 64; vp1 += 64;
            __syncthreads();

            // QK^T: D-layout row q=(l>>4)*4+r, col t=tb*16+(l&15)
            f32x4 sf[4];
            #pragma unroll
            for (int tb = 0; tb < 4; ++tb) {
                f32x4 s = {};
                #pragma unroll
                for (int kc = 0; kc < 2; ++kc) {
                    int row = tb * 16 + lrow;
                    int slot = (kc * 4 + lslot) ^ (row & 7);
                    bf16x8 kf = *reinterpret_cast<const bf16x8*>(ks + row * 128 + slot * 16);
                    s = mfma16(qf[kc], kf, s);
                }
                sf[tb] = s;
            }

            const bool diag = (kt == qt);
            #pragma unroll
            for (int r = 0; r < 4; ++r) {
                float mx = -1e30f;
                #pragma unroll
                for (int tb = 0; tb < 4; ++tb) {
                    float v = sf[tb][r] * SCL2E;     // score * 0.125 * log2e
                    if (diag) {
                        int tg = kv0 + tb * 16 + lrow;
                        if (tg > qg0 + r) v = -1e30f;
                    }
                    sf[tb][r] = v;
                    mx = fmaxf(mx, v);
                }
                mx = fmaxf(mx, __shfl_xor(mx, 1));
                mx = fmaxf(mx, __shfl_xor(mx, 2));
                mx = fmaxf(mx, __shfl_xor(mx, 4));
                mx = fmaxf(mx, __shfl_xor(mx, 8));
                float mnew = fmaxf(mrow[r], mx);
                float alpha = exp2f(mrow[r] - mnew);
                float psum = 0.f;
                #pragma unroll
                for (int tb = 0; tb < 4; ++tb) {
                    float p = exp2f(sf[tb][r] - mnew);
                    sf[tb][r] = p;
                    psum += p;
                }
                psum += __shfl_xor(psum, 1);
                psum += __shfl_xor(psum, 2);
                psum += __shfl_xor(psum, 4);
                psum += __shfl_xor(psum, 8);
                mrow[r] = mnew;
                lsum[r] = lsum[r] * alpha + psum;
                #pragma unroll
                for (int db = 0; db < 4; ++db) oacc[db][r] *= alpha;
                int q = (l >> 4) * 4 + r;
                #pragma unroll
                for (int tb = 0; tb < 4; ++tb) {
                    int t = tb * 16 + lrow;
                    *reinterpret_cast<__bf16*>(Pl[w] + q * 128 + ((t * 2) ^ ((q & 7) << 4))) =
                        (__bf16)sf[tb][r];
                }
            }

            // PV
            #pragma unroll
            for (int tc = 0; tc < 2; ++tc) {
                int q = lrow;
                int pslot = (tc * 4 + lslot) ^ (q & 7);
                bf16x8 pf = *reinterpret_cast<const bf16x8*>(Pl[w] + q * 128 + pslot * 16);
                #pragma unroll
                for (int db = 0; db < 4; ++db) {
                    int vrow = db * 16 + lrow;
                    int vslot = (tc * 4 + lslot) ^ (vrow & 7);
                    bf16x8 vf = *reinterpret_cast<const bf16x8*>(vs + vrow * 128 + vslot * 16);
                    oacc[db] = mfma16(pf, vf, oacc[db]);
                }
            }
            __syncthreads();
        }

        // epilogue: Oa[b, s=q, h*64+d] bf16
        #pragma unroll
        for (int db = 0; db < 4; ++db) {
            #pragma unroll
            for (int r = 0; r < 4; ++r) {
                int q = qg0 + r;
                int d = db * 16 + lrow;
                float v = oacc[db][r] / lsum[r];
                Oa[((size_t)(b * SS + q)) * EDIM + h * HD + d] = (__bf16)v;
            }
        }
    }
}

// ---------------- launch ----------------
extern "C" void kernel_launch(void* const* d_in, const int* in_sizes, int n_in,
                              void* d_out, int out_size, void* d_ws, size_t ws_size,
                              hipStream_t stream) {
    const float* x  = (const float*)d_in[0];
    const float* Wq = (const float*)d_in[1];
    const float* bq = (const float*)d_in[2];
    const float* Wk = (const float*)d_in[3];
    const float* bk = (const float*)d_in[4];
    const float* Wv = (const float*)d_in[5];
    const float* bv = (const float*)d_in[6];
    const float* Wo = (const float*)d_in[7];
    const float* bo = (const float*)d_in[8];

    char* ws = (char*)d_ws;
    const size_t SZ_XB  = (size_t)MROWS * EDIM * 2;       // 16 MB
    const size_t SZ_W   = (size_t)EDIM * EDIM * 2;        // 2 MB
    const size_t SZ_QKV = (size_t)BB * NH * SS * HD * 2;  // 16 MB

    __bf16* xb  = (__bf16*)(ws);
    __bf16* wqb = (__bf16*)(ws + SZ_XB);
    __bf16* wkb = (__bf16*)(ws + SZ_XB + SZ_W);
    __bf16* wvb = (__bf16*)(ws + SZ_XB + 2 * SZ_W);
    __bf16* wob = (__bf16*)(ws + SZ_XB + 3 * SZ_W);
    __bf16* Qb  = (__bf16*)(ws + SZ_XB + 4 * SZ_W);
    __bf16* Kb  = (__bf16*)(ws + SZ_XB + 4 * SZ_W + SZ_QKV);
    __bf16* Vtb = (__bf16*)(ws + SZ_XB + 4 * SZ_W + 2 * SZ_QKV);
    __bf16* Oab = (__bf16*)(ws + SZ_XB + 4 * SZ_W + 3 * SZ_QKV);

    cvt_kernel<<<MROWS * EDIM / 1024, 256, 0, stream>>>(x, xb, MROWS * EDIM);
    cvt_kernel<<<EDIM * EDIM / 1024, 256, 0, stream>>>(Wq, wqb, EDIM * EDIM);
    cvt_kernel<<<EDIM * EDIM / 1024, 256, 0, stream>>>(Wk, wkb, EDIM * EDIM);
    cvt_kernel<<<EDIM * EDIM / 1024, 256, 0, stream>>>(Wv, wvb, EDIM * EDIM);
    cvt_kernel<<<EDIM * EDIM / 1024, 256, 0, stream>>>(Wo, wob, EDIM * EDIM);

    dim3 ggrid(MROWS / 128, EDIM / 128);
    gemm_bt<<<ggrid, 256, 0, stream>>>(xb, wqb, bq, (void*)Qb, 0);
    gemm_bt<<<ggrid, 256, 0, stream>>>(xb, wkb, bk, (void*)Kb, 0);
    gemm_bt<<<ggrid, 256, 0, stream>>>(xb, wvb, bv, (void*)Vtb, 2);

    attn_kernel<<<dim3(BB * NH, 16), 256, 0, stream>>>(Qb, Kb, Vtb, Oab);

    gemm_bt<<<ggrid, 256, 0, stream>>>(Oab, wob, bo, d_out, 3);
}

// Round 8
// 236.024 us; speedup vs baseline: 1.1969x; 1.1969x over previous
//
#include <hip/hip_runtime.h>
#include <hip/hip_bf16.h>
#include <stdint.h>

// Problem constants
#define EDIM 1024
#define NH   16
#define HD   64
#define BB   4
#define SS   2048
#define MROWS (BB*SS)   // 8192

typedef __bf16 bf16x8 __attribute__((ext_vector_type(8)));
typedef __bf16 bf16x4 __attribute__((ext_vector_type(4)));
typedef float  f32x4  __attribute__((ext_vector_type(4)));

__device__ __forceinline__ void async16(const void* g, void* lds) {
    __builtin_amdgcn_global_load_lds((__attribute__((address_space(1))) void*)(g),
                                     (__attribute__((address_space(3))) void*)(lds),
                                     16, 0, 0);
}

__device__ __forceinline__ f32x4 mfma16(bf16x8 a, bf16x8 b, f32x4 c) {
    return __builtin_amdgcn_mfma_f32_16x16x32_bf16(a, b, c, 0, 0, 0);
}

// 16-lane all-reduce via DPP (VALU pipe, no LDS).
// DPP ctrl must be an immediate -> template parameter.
template <int CTRL>
__device__ __forceinline__ float dpp_max_hop(float x) {
    int v = __builtin_amdgcn_update_dpp(0, __float_as_int(x), CTRL, 0xf, 0xf, true);
    return fmaxf(x, __int_as_float(v));
}
template <int CTRL>
__device__ __forceinline__ float dpp_add_hop(float x) {
    int v = __builtin_amdgcn_update_dpp(0, __float_as_int(x), CTRL, 0xf, 0xf, true);
    return x + __int_as_float(v);
}
// hops: quad_perm[1,0,3,2]=0xB1 (xor1), quad_perm[2,3,0,1]=0x4E (xor2),
// row_half_mirror=0x141 (xor4), row_mirror=0x140 (xor8) — covers 16 lanes.
__device__ __forceinline__ float reduce16_max(float x) {
    x = dpp_max_hop<0xB1>(x);
    x = dpp_max_hop<0x4E>(x);
    x = dpp_max_hop<0x141>(x);
    x = dpp_max_hop<0x140>(x);
    return x;
}
__device__ __forceinline__ float reduce16_add(float x) {
    x = dpp_add_hop<0xB1>(x);
    x = dpp_add_hop<0x4E>(x);
    x = dpp_add_hop<0x141>(x);
    x = dpp_add_hop<0x140>(x);
    return x;
}

// ---------------- fp32 -> bf16 conversion (vectorized) ----------------
__global__ __launch_bounds__(256) void cvt_kernel(const float* __restrict__ s,
                                                  __bf16* __restrict__ d, int n) {
    int i = (blockIdx.x * 256 + threadIdx.x) * 4;
    if (i < n) {
        float4 v = *reinterpret_cast<const float4*>(s + i);
        bf16x4 o;
        o.x = (__bf16)v.x; o.y = (__bf16)v.y; o.z = (__bf16)v.z; o.w = (__bf16)v.w;
        *reinterpret_cast<bf16x4*>(d + i) = o;
    }
}

// ---------------- GEMM: C[m][n] = sum_k A[m][k]*W[n][k] + bias[n] ----------------
__global__ __launch_bounds__(256) void gemm_bt(const __bf16* __restrict__ A,
                                               const __bf16* __restrict__ W,
                                               const float* __restrict__ bias,
                                               void* __restrict__ dst, int mode) {
    __shared__ char As[128 * 64];  // 128 rows x 32 bf16 (64B), XOR-swizzled slots
    __shared__ char Bs[128 * 64];

    const int tid = threadIdx.x;
    const int w = tid >> 6, l = tid & 63;
    const int bm = blockIdx.x * 128, bn = blockIdx.y * 128;
    const int wm = (w >> 1) * 64, wn = (w & 1) * 64;

    f32x4 acc[4][4] = {};

    const int lrow = l & 15;
    const int lslot = l >> 4;

    for (int kt = 0; kt < EDIM / 32; ++kt) {
        const int k0 = kt * 32;
        #pragma unroll
        for (int i = 0; i < 2; ++i) {
            int c = i * 256 + tid;
            int row = c >> 2, cb = c & 3;
            int gk = k0 + ((cb ^ (row & 3)) << 3);   // pre-swizzled global source
            async16(A + (size_t)(bm + row) * EDIM + gk, As + (i * 256 + w * 64) * 16);
            async16(W + (size_t)(bn + row) * EDIM + gk, Bs + (i * 256 + w * 64) * 16);
        }
        __syncthreads();

        bf16x8 af[4], bfr[4];
        #pragma unroll
        for (int mf = 0; mf < 4; ++mf) {
            int row = wm + mf * 16 + lrow;
            af[mf] = *reinterpret_cast<const bf16x8*>(As + row * 64 + ((lslot ^ (row & 3)) << 4));
        }
        #pragma unroll
        for (int nf = 0; nf < 4; ++nf) {
            int row = wn + nf * 16 + lrow;
            bfr[nf] = *reinterpret_cast<const bf16x8*>(Bs + row * 64 + ((lslot ^ (row & 3)) << 4));
        }
        #pragma unroll
        for (int mf = 0; mf < 4; ++mf)
            #pragma unroll
            for (int nf = 0; nf < 4; ++nf)
                acc[mf][nf] = mfma16(af[mf], bfr[nf], acc[mf][nf]);
        __syncthreads();
    }

    #pragma unroll
    for (int nf = 0; nf < 4; ++nf) {
        int ng = bn + wn + nf * 16 + lrow;
        float bv = bias[ng];
        #pragma unroll
        for (int mf = 0; mf < 4; ++mf) {
            #pragma unroll
            for (int r = 0; r < 4; ++r) {
                int mg = bm + wm + mf * 16 + (l >> 4) * 4 + r;
                float v = acc[mf][nf][r] + bv;
                if (mode == 3) {
                    ((float*)dst)[(size_t)mg * EDIM + ng] = v;
                } else {
                    int b = mg >> 11, s = mg & 2047;
                    int h = ng >> 6, d = ng & 63;
                    size_t idx;
                    if (mode == 2) idx = ((size_t)(b * NH + h) * HD + d) * SS + s;
                    else           idx = ((size_t)(b * NH + h) * SS + s) * HD + d;
                    ((__bf16*)dst)[idx] = (__bf16)v;
                }
            }
        }
    }
}

// ---------------- Flash attention (causal) ----------------
// Q,K: [B,H,S,D] bf16.  Vt: [B,H,D,S] bf16.  Oa: [B,S,H*D] bf16.
// 4 waves/block, wave owns 16 q-rows of a 64-row q-tile; KV tiles of 64.
// qt = 31 - blockIdx.y so longest blocks launch first (drain-tail packing).
#define SCL2E 0.18033688f   /* 0.125 * log2(e) */

__global__ __launch_bounds__(256) void attn_kernel(const __bf16* __restrict__ Q,
                                                   const __bf16* __restrict__ K,
                                                   const __bf16* __restrict__ Vt,
                                                   __bf16* __restrict__ Oa) {
    __shared__ char ks[64 * 128];      // K tile: row t (64 d * 2B), swizzled
    __shared__ char vs[64 * 128];      // Vt tile: row d (64 t * 2B), swizzled
    __shared__ char Pl[4][16 * 128];   // per-wave P: row q (64 t * 2B), swizzled

    const int bh = blockIdx.x;          // 0..63
    const int qt = 31 - blockIdx.y;     // longest first
    const int tid = threadIdx.x;
    const int w = tid >> 6, l = tid & 63;
    const int lrow = l & 15, lslot = l >> 4;

    const __bf16* Qp = Q + (size_t)bh * (SS * HD);
    const __bf16* Kp = K + (size_t)bh * (SS * HD);
    const __bf16* Vp = Vt + (size_t)bh * (HD * SS);

    // staging lane constants (chunk c = i*256+tid, i in {0,1})
    const int rowS0 = tid >> 3;
    const int rowS1 = (256 + tid) >> 3;
    const int cb = tid & 7;             // same for both chunks
    const int gs0 = (cb ^ (rowS0 & 7)) << 3;
    const int gs1 = (cb ^ (rowS1 & 7)) << 3;
    char* ldst0 = (char*)ks + (w * 64) * 16;
    char* ldst1 = (char*)ks + (256 + w * 64) * 16;
    char* ldsv0 = (char*)vs + (w * 64) * 16;
    char* ldsv1 = (char*)vs + (256 + w * 64) * 16;

    // Q fragments (A operand), in registers for the whole kernel
    const int qrow = qt * 64 + w * 16 + lrow;
    bf16x8 qf[2];
    qf[0] = *reinterpret_cast<const bf16x8*>(Qp + (size_t)qrow * HD + lslot * 8);
    qf[1] = *reinterpret_cast<const bf16x8*>(Qp + (size_t)qrow * HD + 32 + lslot * 8);

    f32x4 oacc[4] = {};
    float mrow[4] = {-1e30f, -1e30f, -1e30f, -1e30f};
    float lsum[4] = {0.f, 0.f, 0.f, 0.f};   // PER-LANE PARTIAL (reduced in epilogue)

    const int qg0 = qt * 64 + w * 16 + (l >> 4) * 4;
    const int ntiles = qt + 1;

    // strength-reduced global source pointers
    const __bf16* kp0 = Kp + (size_t)rowS0 * HD + gs0;
    const __bf16* kp1 = Kp + (size_t)rowS1 * HD + gs1;
    const __bf16* vp0 = Vp + (size_t)rowS0 * SS + gs0;
    const __bf16* vp1 = Vp + (size_t)rowS1 * SS + gs1;

    for (int kt = 0; kt < ntiles; ++kt) {
        async16(kp0, ldst0);
        async16(kp1, ldst1);
        async16(vp0, ldsv0);
        async16(vp1, ldsv1);
        kp0 += 64 * HD; kp1 += 64 * HD; vp0 += 64; vp1 += 64;
        __syncthreads();

        // QK^T: D-layout row q=(l>>4)*4+r, col t=tb*16+(l&15)
        f32x4 sf[4];
        #pragma unroll
        for (int tb = 0; tb < 4; ++tb) {
            f32x4 s = {};
            #pragma unroll
            for (int kc = 0; kc < 2; ++kc) {
                int row = tb * 16 + lrow;
                int slot = (kc * 4 + lslot) ^ (row & 7);
                bf16x8 kf = *reinterpret_cast<const bf16x8*>(ks + row * 128 + slot * 16);
                s = mfma16(qf[kc], kf, s);
            }
            sf[tb] = s;
        }

        const bool diag = (kt == qt);
        #pragma unroll
        for (int r = 0; r < 4; ++r) {
            #pragma unroll
            for (int tb = 0; tb < 4; ++tb) {
                float v = sf[tb][r] * SCL2E;     // score * 0.125 * log2e
                if (diag) {
                    int tg = kt * 64 + tb * 16 + lrow;
                    if (tg > qg0 + r) v = -1e30f;
                }
                sf[tb][r] = v;
            }
            float mx = fmaxf(fmaxf(sf[0][r], sf[1][r]), fmaxf(sf[2][r], sf[3][r]));
            mx = reduce16_max(mx);               // DPP, VALU pipe
            float mnew = fmaxf(mrow[r], mx);
            float alpha = exp2f(mrow[r] - mnew);
            float psum = 0.f;
            #pragma unroll
            for (int tb = 0; tb < 4; ++tb) {
                float p = exp2f(sf[tb][r] - mnew);
                sf[tb][r] = p;
                psum += p;
            }
            mrow[r] = mnew;
            lsum[r] = lsum[r] * alpha + psum;    // per-lane partial
            #pragma unroll
            for (int db = 0; db < 4; ++db) oacc[db][r] *= alpha;
            int q = (l >> 4) * 4 + r;
            #pragma unroll
            for (int tb = 0; tb < 4; ++tb) {
                int t = tb * 16 + lrow;
                *reinterpret_cast<__bf16*>(Pl[w] + q * 128 + ((t * 2) ^ ((q & 7) << 4))) =
                    (__bf16)sf[tb][r];
            }
        }

        // PV
        #pragma unroll
        for (int tc = 0; tc < 2; ++tc) {
            int q = lrow;
            int pslot = (tc * 4 + lslot) ^ (q & 7);
            bf16x8 pf = *reinterpret_cast<const bf16x8*>(Pl[w] + q * 128 + pslot * 16);
            #pragma unroll
            for (int db = 0; db < 4; ++db) {
                int vrow = db * 16 + lrow;
                int vslot = (tc * 4 + lslot) ^ (vrow & 7);
                bf16x8 vf = *reinterpret_cast<const bf16x8*>(vs + vrow * 128 + vslot * 16);
                oacc[db] = mfma16(pf, vf, oacc[db]);
            }
        }
        __syncthreads();
    }

    // epilogue: finish the deferred row-sum reduction, then store
    const int b = bh >> 4, h = bh & 15;
    #pragma unroll
    for (int r = 0; r < 4; ++r) {
        float inv = 1.0f / reduce16_add(lsum[r]);
        #pragma unroll
        for (int db = 0; db < 4; ++db) {
            int q = qg0 + r;
            int d = db * 16 + lrow;
            Oa[((size_t)(b * SS + q)) * EDIM + h * HD + d] = (__bf16)(oacc[db][r] * inv);
        }
    }
}

// ---------------- launch ----------------
extern "C" void kernel_launch(void* const* d_in, const int* in_sizes, int n_in,
                              void* d_out, int out_size, void* d_ws, size_t ws_size,
                              hipStream_t stream) {
    const float* x  = (const float*)d_in[0];
    const float* Wq = (const float*)d_in[1];
    const float* bq = (const float*)d_in[2];
    const float* Wk = (const float*)d_in[3];
    const float* bk = (const float*)d_in[4];
    const float* Wv = (const float*)d_in[5];
    const float* bv = (const float*)d_in[6];
    const float* Wo = (const float*)d_in[7];
    const float* bo = (const float*)d_in[8];

    char* ws = (char*)d_ws;
    const size_t SZ_XB  = (size_t)MROWS * EDIM * 2;       // 16 MB
    const size_t SZ_W   = (size_t)EDIM * EDIM * 2;        // 2 MB
    const size_t SZ_QKV = (size_t)BB * NH * SS * HD * 2;  // 16 MB

    __bf16* xb  = (__bf16*)(ws);
    __bf16* wqb = (__bf16*)(ws + SZ_XB);
    __bf16* wkb = (__bf16*)(ws + SZ_XB + SZ_W);
    __bf16* wvb = (__bf16*)(ws + SZ_XB + 2 * SZ_W);
    __bf16* wob = (__bf16*)(ws + SZ_XB + 3 * SZ_W);
    __bf16* Qb  = (__bf16*)(ws + SZ_XB + 4 * SZ_W);
    __bf16* Kb  = (__bf16*)(ws + SZ_XB + 4 * SZ_W + SZ_QKV);
    __bf16* Vtb = (__bf16*)(ws + SZ_XB + 4 * SZ_W + 2 * SZ_QKV);
    __bf16* Oab = (__bf16*)(ws + SZ_XB + 4 * SZ_W + 3 * SZ_QKV);

    cvt_kernel<<<MROWS * EDIM / 1024, 256, 0, stream>>>(x, xb, MROWS * EDIM);
    cvt_kernel<<<EDIM * EDIM / 1024, 256, 0, stream>>>(Wq, wqb, EDIM * EDIM);
    cvt_kernel<<<EDIM * EDIM / 1024, 256, 0, stream>>>(Wk, wkb, EDIM * EDIM);
    cvt_kernel<<<EDIM * EDIM / 1024, 256, 0, stream>>>(Wv, wvb, EDIM * EDIM);
    cvt_kernel<<<EDIM * EDIM / 1024, 256, 0, stream>>>(Wo, wob, EDIM * EDIM);

    dim3 ggrid(MROWS / 128, EDIM / 128);
    gemm_bt<<<ggrid, 256, 0, stream>>>(xb, wqb, bq, (void*)Qb, 0);
    gemm_bt<<<ggrid, 256, 0, stream>>>(xb, wkb, bk, (void*)Kb, 0);
    gemm_bt<<<ggrid, 256, 0, stream>>>(xb, wvb, bv, (void*)Vtb, 2);

    attn_kernel<<<dim3(BB * NH, SS / 64), 256, 0, stream>>>(Qb, Kb, Vtb, Oab);

    gemm_bt<<<ggrid, 256, 0, stream>>>(Oab, wob, bo, d_out, 3);
}

// Round 13
// 229.608 us; speedup vs baseline: 1.2303x; 1.0279x over previous
//
#include <hip/hip_runtime.h>
#include <hip/hip_bf16.h>
#include <stdint.h>

// Problem constants
#define EDIM 1024
#define NH   16
#define HD   64
#define BB   4
#define SS   2048
#define MROWS (BB*SS)   // 8192

typedef __bf16 bf16x8 __attribute__((ext_vector_type(8)));
typedef __bf16 bf16x4 __attribute__((ext_vector_type(4)));
typedef float  f32x4  __attribute__((ext_vector_type(4)));
typedef float  f32x16 __attribute__((ext_vector_type(16)));
typedef int    int2v  __attribute__((ext_vector_type(2)));

__device__ __forceinline__ void async16(const void* g, void* lds) {
    __builtin_amdgcn_global_load_lds((__attribute__((address_space(1))) void*)(g),
                                     (__attribute__((address_space(3))) void*)(lds),
                                     16, 0, 0);
}

__device__ __forceinline__ f32x4 mfma16(bf16x8 a, bf16x8 b, f32x4 c) {
    return __builtin_amdgcn_mfma_f32_16x16x32_bf16(a, b, c, 0, 0, 0);
}
__device__ __forceinline__ f32x16 mfma32(bf16x8 a, bf16x8 b, f32x16 c) {
    return __builtin_amdgcn_mfma_f32_32x32x16_bf16(a, b, c, 0, 0, 0);
}

// pack two f32 -> one u32 of 2 bf16 (compiler emits v_cvt_pk_bf16_f32)
__device__ __forceinline__ int pkbf16(float a, float b) {
    union { __bf16 h[2]; int i; } u;
    u.h[0] = (__bf16)a; u.h[1] = (__bf16)b;
    return u.i;
}

// ---------------- fp32 -> bf16 conversion (vectorized) ----------------
__global__ __launch_bounds__(256) void cvt_kernel(const float* __restrict__ s,
                                                  __bf16* __restrict__ d, int n) {
    int i = (blockIdx.x * 256 + threadIdx.x) * 4;
    if (i < n) {
        float4 v = *reinterpret_cast<const float4*>(s + i);
        bf16x4 o;
        o.x = (__bf16)v.x; o.y = (__bf16)v.y; o.z = (__bf16)v.z; o.w = (__bf16)v.w;
        *reinterpret_cast<bf16x4*>(d + i) = o;
    }
}

// ---------------- GEMM: C[m][n] = sum_k A[m][k]*W[n][k] + bias[n] ----------------
__global__ __launch_bounds__(256) void gemm_bt(const __bf16* __restrict__ A,
                                               const __bf16* __restrict__ W,
                                               const float* __restrict__ bias,
                                               void* __restrict__ dst, int mode) {
    __shared__ char As[128 * 64];  // 128 rows x 32 bf16 (64B), XOR-swizzled slots
    __shared__ char Bs[128 * 64];

    const int tid = threadIdx.x;
    const int w = tid >> 6, l = tid & 63;
    const int bm = blockIdx.x * 128, bn = blockIdx.y * 128;
    const int wm = (w >> 1) * 64, wn = (w & 1) * 64;

    f32x4 acc[4][4] = {};

    const int lrow = l & 15;
    const int lslot = l >> 4;

    for (int kt = 0; kt < EDIM / 32; ++kt) {
        const int k0 = kt * 32;
        #pragma unroll
        for (int i = 0; i < 2; ++i) {
            int c = i * 256 + tid;
            int row = c >> 2, cb = c & 3;
            int gk = k0 + ((cb ^ (row & 3)) << 3);   // pre-swizzled global source
            async16(A + (size_t)(bm + row) * EDIM + gk, As + (i * 256 + w * 64) * 16);
            async16(W + (size_t)(bn + row) * EDIM + gk, Bs + (i * 256 + w * 64) * 16);
        }
        __syncthreads();

        bf16x8 af[4], bfr[4];
        #pragma unroll
        for (int mf = 0; mf < 4; ++mf) {
            int row = wm + mf * 16 + lrow;
            af[mf] = *reinterpret_cast<const bf16x8*>(As + row * 64 + ((lslot ^ (row & 3)) << 4));
        }
        #pragma unroll
        for (int nf = 0; nf < 4; ++nf) {
            int row = wn + nf * 16 + lrow;
            bfr[nf] = *reinterpret_cast<const bf16x8*>(Bs + row * 64 + ((lslot ^ (row & 3)) << 4));
        }
        #pragma unroll
        for (int mf = 0; mf < 4; ++mf)
            #pragma unroll
            for (int nf = 0; nf < 4; ++nf)
                acc[mf][nf] = mfma16(af[mf], bfr[nf], acc[mf][nf]);
        __syncthreads();
    }

    #pragma unroll
    for (int nf = 0; nf < 4; ++nf) {
        int ng = bn + wn + nf * 16 + lrow;
        float bv = bias[ng];
        #pragma unroll
        for (int mf = 0; mf < 4; ++mf) {
            #pragma unroll
            for (int r = 0; r < 4; ++r) {
                int mg = bm + wm + mf * 16 + (l >> 4) * 4 + r;
                float v = acc[mf][nf][r] + bv;
                if (mode == 3) {
                    ((float*)dst)[(size_t)mg * EDIM + ng] = v;
                } else {
                    int b = mg >> 11, s = mg & 2047;
                    int h = ng >> 6, d = ng & 63;
                    size_t idx;
                    if (mode == 2) idx = ((size_t)(b * NH + h) * HD + d) * SS + s;
                    else           idx = ((size_t)(b * NH + h) * SS + s) * HD + d;
                    ((__bf16*)dst)[idx] = (__bf16)v;
                }
            }
        }
    }
}

// ---------------- Flash attention (causal, swapped-QK^T, in-register softmax) ----
// Q,K: [B,H,S,D] bf16.  Vt: [B,H,D,S] bf16.  Oa: [B,S,H*D] bf16.
// 8 warps/block (512 thr). Warp owns 32 q-rows of a 256-row q-tile. KV tiles 64.
// QK^T = mfma32(A=K, B=Q): lane holds S[t][q=lane&31].
// PV computed TRANSPOSED: O^T = V^T·P^T via mfma32(A=Vt, B=P^T) so the D-layout
// col = q = lane&31 -> softmax state (m, lsum, alpha) is fully lane-local for
// both the per-tile rescale and the final division (the R10 bug was rescaling
// O-rows q=crow(r) with alpha of row q=lane&31).
#define SCL2E 0.18033688f   /* 0.125 * log2(e) */

__global__ __launch_bounds__(512) void attn_kernel(const __bf16* __restrict__ Q,
                                                   const __bf16* __restrict__ K,
                                                   const __bf16* __restrict__ Vt,
                                                   __bf16* __restrict__ Oa) {
    __shared__ char ks[64 * 128];      // K tile:  row t (64 d * 2B), swizzled slots
    __shared__ char vs[64 * 128];      // Vt tile: row d (64 t * 2B), swizzled slots

    const int bh = blockIdx.x;          // 0..63
    const int qt = 7 - blockIdx.y;      // 0..7, longest first
    const int tid = threadIdx.x;
    const int w = tid >> 6;             // warp 0..7
    const int l = tid & 63;
    const int lo = l & 31;
    const int hi = l >> 5;

    const __bf16* Qp = Q + (size_t)bh * (SS * HD);
    const __bf16* Kp = K + (size_t)bh * (SS * HD);
    const __bf16* Vp = Vt + (size_t)bh * (HD * SS);

    // Q B-fragments: col=q=lo, k = d = kc*16 + hi*8 + j  (4 frags cover D=64)
    const int qg = qt * 256 + w * 32 + lo;          // this lane's q-row
    bf16x8 qf[4];
    #pragma unroll
    for (int kc = 0; kc < 4; ++kc)
        qf[kc] = *reinterpret_cast<const bf16x8*>(Qp + (size_t)qg * HD + kc * 16 + hi * 8);

    // staging: 512 chunks of 16B per matrix; one per thread
    const int rowS = tid >> 3, cbS = tid & 7;
    const int gsS = (cbS ^ (rowS & 7)) << 3;        // pre-swizzled source offset (elems)
    char* ldsK = (char*)ks + w * 1024;              // wave-uniform base; lane*16 auto
    char* ldsV = (char*)vs + w * 1024;
    const __bf16* kp = Kp + (size_t)rowS * HD + gsS;
    const __bf16* vp = Vp + (size_t)rowS * SS + gsS;

    f32x16 oacc[2] = {};                 // O^T[d = db*32 + crow(r)+4hi][q = lo]
    float mrow = -1e30f;
    float lsum = 0.f;

    const int qwlo = qt * 256 + w * 32;  // warp q-range
    const int qwhi = qwlo + 31;
    const int ntiles = 4 * qt + 4;

    for (int kt = 0; kt < ntiles; ++kt) {
        const int kv0 = kt * 64;
        async16(kp, ldsK);
        async16(vp, ldsV);
        kp += 64 * HD; vp += 64;
        __syncthreads();

        if (kv0 <= qwhi) {               // skip fully-masked tiles (warp-uniform)
            // QK^T: S[t][q], acc[tb]: t = tb*32 + crow(r) + 4*hi, q = lo
            f32x16 acc[2] = {};
            #pragma unroll
            for (int tb = 0; tb < 2; ++tb) {
                const int t = tb * 32 + lo;
                const char* krow = ks + t * 128;
                const int tx = (t & 7);
                #pragma unroll
                for (int kc = 0; kc < 4; ++kc) {
                    bf16x8 kf = *reinterpret_cast<const bf16x8*>(krow + ((2 * kc + hi) ^ tx) * 16);
                    acc[tb] = mfma32(kf, qf[kc], acc[tb]);
                }
            }

            // causal mask (raw scores), only near the diagonal
            if (kv0 + 63 > qwlo) {
                #pragma unroll
                for (int tb = 0; tb < 2; ++tb)
                    #pragma unroll
                    for (int r = 0; r < 16; ++r) {
                        int t = kv0 + tb * 32 + ((r & 3) + 8 * (r >> 2)) + 4 * hi;
                        if (t > qg) acc[tb][r] = -1e30f;
                    }
            }

            // in-register online softmax (scalar m/lsum per lane; row = q = lo)
            float mx = acc[0][0];
            #pragma unroll
            for (int r = 1; r < 16; ++r) mx = fmaxf(mx, acc[0][r]);
            #pragma unroll
            for (int r = 0; r < 16; ++r) mx = fmaxf(mx, acc[1][r]);
            mx = fmaxf(mx, __shfl_xor(mx, 32));
            float mnew = fmaxf(mrow, mx * SCL2E);
            float alpha = exp2f(mrow - mnew);
            float psum = 0.f;
            #pragma unroll
            for (int tb = 0; tb < 2; ++tb)
                #pragma unroll
                for (int r = 0; r < 16; ++r) {
                    float p = exp2f(fmaf(acc[tb][r], SCL2E, -mnew));
                    acc[tb][r] = p;
                    psum += p;
                }
            mrow = mnew;
            lsum = lsum * alpha + psum;
            // lane-local rescale: every oacc element is column q = lo
            oacc[0] *= alpha;
            oacc[1] *= alpha;

            // P -> bf16 fragments via cvt_pk + permlane32_swap:
            // lane (lo,hi) gets P[q=lo][t = 16*ks2 + 8*hi + j]
            bf16x8 pa[4];
            #pragma unroll
            for (int ks2 = 0; ks2 < 4; ++ks2) {
                const int tb = ks2 >> 1, rb = (ks2 & 1) * 8;
                int a0 = pkbf16(acc[tb][rb + 0], acc[tb][rb + 1]);
                int b0 = pkbf16(acc[tb][rb + 4], acc[tb][rb + 5]);
                int a1 = pkbf16(acc[tb][rb + 2], acc[tb][rb + 3]);
                int b1 = pkbf16(acc[tb][rb + 6], acc[tb][rb + 7]);
                int2v s1 = __builtin_amdgcn_permlane32_swap(a0, b0, false, false);
                int2v s2 = __builtin_amdgcn_permlane32_swap(a1, b1, false, false);
                union { int i[4]; bf16x8 v; } u;
                u.i[0] = s1[0]; u.i[1] = s2[0]; u.i[2] = s1[1]; u.i[3] = s2[1];
                pa[ks2] = u.v;
            }

            // PV transposed: O^T[d][q] += V^T[d][t] * P^T[t][q]
            // A = Vt rows (m=d), B = pa (k=t, n=q=lo)
            #pragma unroll
            for (int ks2 = 0; ks2 < 4; ++ks2) {
                #pragma unroll
                for (int db = 0; db < 2; ++db) {
                    const int d = db * 32 + lo;
                    bf16x8 vb = *reinterpret_cast<const bf16x8*>(
                        vs + d * 128 + (((2 * ks2 + hi) ^ (d & 7)) * 16));
                    oacc[db] = mfma32(vb, pa[ks2], oacc[db]);
                }
            }
        }
        __syncthreads();
    }

    // epilogue: lane-local normalize; store O[q=qg][d] with 8B-packed stores.
    // Lane's 16 values per db: d = db*32 + (r&3) + 8*(r>>2) + 4*hi.
    const int b = bh >> 4, h = bh & 15;
    float lsumt = lsum + __shfl_xor(lsum, 32);   // halves hold partial sums over t
    float inv = 1.0f / lsumt;
    __bf16* orow = Oa + ((size_t)(b * SS + qg)) * EDIM + h * HD;
    #pragma unroll
    for (int db = 0; db < 2; ++db) {
        #pragma unroll
        for (int g = 0; g < 4; ++g) {
            int d0 = db * 32 + g * 8 + 4 * hi;
            bf16x4 o4;
            o4.x = (__bf16)(oacc[db][g * 4 + 0] * inv);
            o4.y = (__bf16)(oacc[db][g * 4 + 1] * inv);
            o4.z = (__bf16)(oacc[db][g * 4 + 2] * inv);
            o4.w = (__bf16)(oacc[db][g * 4 + 3] * inv);
            *reinterpret_cast<bf16x4*>(orow + d0) = o4;
        }
    }
}

// ---------------- launch ----------------
extern "C" void kernel_launch(void* const* d_in, const int* in_sizes, int n_in,
                              void* d_out, int out_size, void* d_ws, size_t ws_size,
                              hipStream_t stream) {
    const float* x  = (const float*)d_in[0];
    const float* Wq = (const float*)d_in[1];
    const float* bq = (const float*)d_in[2];
    const float* Wk = (const float*)d_in[3];
    const float* bk = (const float*)d_in[4];
    const float* Wv = (const float*)d_in[5];
    const float* bv = (const float*)d_in[6];
    const float* Wo = (const float*)d_in[7];
    const float* bo = (const float*)d_in[8];

    char* ws = (char*)d_ws;
    const size_t SZ_XB  = (size_t)MROWS * EDIM * 2;       // 16 MB
    const size_t SZ_W   = (size_t)EDIM * EDIM * 2;        // 2 MB
    const size_t SZ_QKV = (size_t)BB * NH * SS * HD * 2;  // 16 MB

    __bf16* xb  = (__bf16*)(ws);
    __bf16* wqb = (__bf16*)(ws + SZ_XB);
    __bf16* wkb = (__bf16*)(ws + SZ_XB + SZ_W);
    __bf16* wvb = (__bf16*)(ws + SZ_XB + 2 * SZ_W);
    __bf16* wob = (__bf16*)(ws + SZ_XB + 3 * SZ_W);
    __bf16* Qb  = (__bf16*)(ws + SZ_XB + 4 * SZ_W);
    __bf16* Kb  = (__bf16*)(ws + SZ_XB + 4 * SZ_W + SZ_QKV);
    __bf16* Vtb = (__bf16*)(ws + SZ_XB + 4 * SZ_W + 2 * SZ_QKV);
    __bf16* Oab = (__bf16*)(ws + SZ_XB + 4 * SZ_W + 3 * SZ_QKV);

    cvt_kernel<<<MROWS * EDIM / 1024, 256, 0, stream>>>(x, xb, MROWS * EDIM);
    cvt_kernel<<<EDIM * EDIM / 1024, 256, 0, stream>>>(Wq, wqb, EDIM * EDIM);
    cvt_kernel<<<EDIM * EDIM / 1024, 256, 0, stream>>>(Wk, wkb, EDIM * EDIM);
    cvt_kernel<<<EDIM * EDIM / 1024, 256, 0, stream>>>(Wv, wvb, EDIM * EDIM);
    cvt_kernel<<<EDIM * EDIM / 1024, 256, 0, stream>>>(Wo, wob, EDIM * EDIM);

    dim3 ggrid(MROWS / 128, EDIM / 128);
    gemm_bt<<<ggrid, 256, 0, stream>>>(xb, wqb, bq, (void*)Qb, 0);
    gemm_bt<<<ggrid, 256, 0, stream>>>(xb, wkb, bk, (void*)Kb, 0);
    gemm_bt<<<ggrid, 256, 0, stream>>>(xb, wvb, bv, (void*)Vtb, 2);

    attn_kernel<<<dim3(BB * NH, 8), 512, 0, stream>>>(Qb, Kb, Vtb, Oab);

    gemm_bt<<<ggrid, 256, 0, stream>>>(Oab, wob, bo, d_out, 3);
}

// Round 14
// 223.859 us; speedup vs baseline: 1.2619x; 1.0257x over previous
//
#include <hip/hip_runtime.h>
#include <hip/hip_bf16.h>
#include <stdint.h>

// Problem constants
#define EDIM 1024
#define NH   16
#define HD   64
#define BB   4
#define SS   2048
#define MROWS (BB*SS)   // 8192

typedef __bf16 bf16x8 __attribute__((ext_vector_type(8)));
typedef __bf16 bf16x4 __attribute__((ext_vector_type(4)));
typedef float  f32x4  __attribute__((ext_vector_type(4)));
typedef float  f32x16 __attribute__((ext_vector_type(16)));
typedef int    int2v  __attribute__((ext_vector_type(2)));

__device__ __forceinline__ void async16(const void* g, void* lds) {
    __builtin_amdgcn_global_load_lds((__attribute__((address_space(1))) void*)(g),
                                     (__attribute__((address_space(3))) void*)(lds),
                                     16, 0, 0);
}

__device__ __forceinline__ f32x4 mfma16(bf16x8 a, bf16x8 b, f32x4 c) {
    return __builtin_amdgcn_mfma_f32_16x16x32_bf16(a, b, c, 0, 0, 0);
}
__device__ __forceinline__ f32x16 mfma32(bf16x8 a, bf16x8 b, f32x16 c) {
    return __builtin_amdgcn_mfma_f32_32x32x16_bf16(a, b, c, 0, 0, 0);
}

// pack two f32 -> one u32 of 2 bf16 (compiler emits v_cvt_pk_bf16_f32)
__device__ __forceinline__ int pkbf16(float a, float b) {
    union { __bf16 h[2]; int i; } u;
    u.h[0] = (__bf16)a; u.h[1] = (__bf16)b;
    return u.i;
}

// ---------------- fp32 -> bf16 conversion (vectorized) ----------------
__global__ __launch_bounds__(256) void cvt_kernel(const float* __restrict__ s,
                                                  __bf16* __restrict__ d, int n) {
    int i = (blockIdx.x * 256 + threadIdx.x) * 4;
    if (i < n) {
        float4 v = *reinterpret_cast<const float4*>(s + i);
        bf16x4 o;
        o.x = (__bf16)v.x; o.y = (__bf16)v.y; o.z = (__bf16)v.z; o.w = (__bf16)v.w;
        *reinterpret_cast<bf16x4*>(d + i) = o;
    }
}

// ---------------- GEMM: C[m][n] = sum_k A[m][k]*W[n][k] + bias[n] ----------------
__global__ __launch_bounds__(256) void gemm_bt(const __bf16* __restrict__ A,
                                               const __bf16* __restrict__ W,
                                               const float* __restrict__ bias,
                                               void* __restrict__ dst, int mode) {
    __shared__ char As[128 * 64];  // 128 rows x 32 bf16 (64B), XOR-swizzled slots
    __shared__ char Bs[128 * 64];

    const int tid = threadIdx.x;
    const int w = tid >> 6, l = tid & 63;
    const int bm = blockIdx.x * 128, bn = blockIdx.y * 128;
    const int wm = (w >> 1) * 64, wn = (w & 1) * 64;

    f32x4 acc[4][4] = {};

    const int lrow = l & 15;
    const int lslot = l >> 4;

    for (int kt = 0; kt < EDIM / 32; ++kt) {
        const int k0 = kt * 32;
        #pragma unroll
        for (int i = 0; i < 2; ++i) {
            int c = i * 256 + tid;
            int row = c >> 2, cb = c & 3;
            int gk = k0 + ((cb ^ (row & 3)) << 3);   // pre-swizzled global source
            async16(A + (size_t)(bm + row) * EDIM + gk, As + (i * 256 + w * 64) * 16);
            async16(W + (size_t)(bn + row) * EDIM + gk, Bs + (i * 256 + w * 64) * 16);
        }
        __syncthreads();

        bf16x8 af[4], bfr[4];
        #pragma unroll
        for (int mf = 0; mf < 4; ++mf) {
            int row = wm + mf * 16 + lrow;
            af[mf] = *reinterpret_cast<const bf16x8*>(As + row * 64 + ((lslot ^ (row & 3)) << 4));
        }
        #pragma unroll
        for (int nf = 0; nf < 4; ++nf) {
            int row = wn + nf * 16 + lrow;
            bfr[nf] = *reinterpret_cast<const bf16x8*>(Bs + row * 64 + ((lslot ^ (row & 3)) << 4));
        }
        #pragma unroll
        for (int mf = 0; mf < 4; ++mf)
            #pragma unroll
            for (int nf = 0; nf < 4; ++nf)
                acc[mf][nf] = mfma16(af[mf], bfr[nf], acc[mf][nf]);
        __syncthreads();
    }

    #pragma unroll
    for (int nf = 0; nf < 4; ++nf) {
        int ng = bn + wn + nf * 16 + lrow;
        float bv = bias[ng];
        #pragma unroll
        for (int mf = 0; mf < 4; ++mf) {
            #pragma unroll
            for (int r = 0; r < 4; ++r) {
                int mg = bm + wm + mf * 16 + (l >> 4) * 4 + r;
                float v = acc[mf][nf][r] + bv;
                if (mode == 3) {
                    ((float*)dst)[(size_t)mg * EDIM + ng] = v;
                } else {
                    int b = mg >> 11, s = mg & 2047;
                    int h = ng >> 6, d = ng & 63;
                    size_t idx;
                    if (mode == 2) idx = ((size_t)(b * NH + h) * HD + d) * SS + s;
                    else           idx = ((size_t)(b * NH + h) * SS + s) * HD + d;
                    ((__bf16*)dst)[idx] = (__bf16)v;
                }
            }
        }
    }
}

// ---------------- Flash attention (causal, swapped-QK^T, in-register softmax,
//                  double-buffered staging with counted vmcnt) ----
// Q,K: [B,H,S,D] bf16.  Vt: [B,H,D,S] bf16.  Oa: [B,S,H*D] bf16.
// 8 warps/block (512 thr). Warp owns 32 q-rows of a 256-row q-tile. KV tiles 64.
// QK^T = mfma32(A=K, B=Q): lane holds S[t][q=lane&31].
// PV transposed: O^T = V^T·P^T -> softmax state fully lane-local.
// Staging: tile kt+1's loads issued before computing tile kt; raw s_barrier
// (NOT __syncthreads, which drains vmcnt(0)) + s_waitcnt vmcnt(2).
#define SCL2E 0.18033688f   /* 0.125 * log2(e) */

__global__ __launch_bounds__(512) void attn_kernel(const __bf16* __restrict__ Q,
                                                   const __bf16* __restrict__ K,
                                                   const __bf16* __restrict__ Vt,
                                                   __bf16* __restrict__ Oa) {
    __shared__ char ks[2][64 * 128];   // K tiles (dbuf): row t (64 d * 2B), swizzled
    __shared__ char vs[2][64 * 128];   // Vt tiles (dbuf): row d (64 t * 2B), swizzled

    const int bh = blockIdx.x;          // 0..63
    const int qt = 7 - blockIdx.y;      // 0..7, longest first
    const int tid = threadIdx.x;
    const int w = tid >> 6;             // warp 0..7
    const int l = tid & 63;
    const int lo = l & 31;
    const int hi = l >> 5;

    const __bf16* Qp = Q + (size_t)bh * (SS * HD);
    const __bf16* Kp = K + (size_t)bh * (SS * HD);
    const __bf16* Vp = Vt + (size_t)bh * (HD * SS);

    // Q B-fragments: col=q=lo, k = d = kc*16 + hi*8 + j  (4 frags cover D=64)
    const int qg = qt * 256 + w * 32 + lo;          // this lane's q-row
    bf16x8 qf[4];
    #pragma unroll
    for (int kc = 0; kc < 4; ++kc)
        qf[kc] = *reinterpret_cast<const bf16x8*>(Qp + (size_t)qg * HD + kc * 16 + hi * 8);

    // staging: 512 chunks of 16B per matrix; one per thread
    const int rowS = tid >> 3, cbS = tid & 7;
    const int gsS = (cbS ^ (rowS & 7)) << 3;        // pre-swizzled source offset (elems)
    const int wb = w * 1024;                        // wave-uniform LDS base
    const __bf16* kp = Kp + (size_t)rowS * HD + gsS;
    const __bf16* vp = Vp + (size_t)rowS * SS + gsS;

    f32x16 oacc[2] = {};                 // O^T[d = db*32 + crow(r)+4hi][q = lo]
    float mrow = -1e30f;
    float lsum = 0.f;

    const int qwlo = qt * 256 + w * 32;  // warp q-range
    const int qwhi = qwlo + 31;
    const int ntiles = 4 * qt + 4;

    // prologue: stage tile 0 into buffer 0
    async16(kp, ks[0] + wb);
    async16(vp, vs[0] + wb);
    kp += 64 * HD; vp += 64;

    int cur = 0;
    for (int kt = 0; kt < ntiles; ++kt) {
        const int kv0 = kt * 64;
        if (kt + 1 < ntiles) {
            // issue next tile's loads into the other buffer, keep them in flight
            async16(kp, ks[cur ^ 1] + wb);
            async16(vp, vs[cur ^ 1] + wb);
            kp += 64 * HD; vp += 64;
            asm volatile("s_waitcnt vmcnt(2)" ::: "memory");  // current tile landed
        } else {
            asm volatile("s_waitcnt vmcnt(0)" ::: "memory");  // drain last tile
        }
        __builtin_amdgcn_s_barrier();
        __builtin_amdgcn_sched_barrier(0);

        if (kv0 <= qwhi) {               // skip fully-masked tiles (warp-uniform)
            const char* ksb = ks[cur];
            const char* vsb = vs[cur];
            // QK^T: S[t][q], acc[tb]: t = tb*32 + crow(r) + 4*hi, q = lo
            f32x16 acc[2] = {};
            #pragma unroll
            for (int tb = 0; tb < 2; ++tb) {
                const int t = tb * 32 + lo;
                const char* krow = ksb + t * 128;
                const int tx = (t & 7);
                #pragma unroll
                for (int kc = 0; kc < 4; ++kc) {
                    bf16x8 kf = *reinterpret_cast<const bf16x8*>(krow + ((2 * kc + hi) ^ tx) * 16);
                    acc[tb] = mfma32(kf, qf[kc], acc[tb]);
                }
            }

            // causal mask (raw scores), only near the diagonal
            if (kv0 + 63 > qwlo) {
                #pragma unroll
                for (int tb = 0; tb < 2; ++tb)
                    #pragma unroll
                    for (int r = 0; r < 16; ++r) {
                        int t = kv0 + tb * 32 + ((r & 3) + 8 * (r >> 2)) + 4 * hi;
                        if (t > qg) acc[tb][r] = -1e30f;
                    }
            }

            // in-register online softmax (scalar m/lsum per lane; row = q = lo)
            float mx = acc[0][0];
            #pragma unroll
            for (int r = 1; r < 16; ++r) mx = fmaxf(mx, acc[0][r]);
            #pragma unroll
            for (int r = 0; r < 16; ++r) mx = fmaxf(mx, acc[1][r]);
            mx = fmaxf(mx, __shfl_xor(mx, 32));
            float mxs = mx * SCL2E;
            // T13 defer-max: skip rescale while the tile max stays within 8
            // (log2 units) of the running max; P bounded by 2^8, bf16-safe.
            if (!__all(mxs <= mrow + 8.0f)) {
                float mnew = fmaxf(mrow, mxs);
                float alpha = exp2f(mrow - mnew);
                mrow = mnew;
                lsum *= alpha;
                oacc[0] *= alpha;
                oacc[1] *= alpha;
            }
            float psum = 0.f;
            #pragma unroll
            for (int tb = 0; tb < 2; ++tb)
                #pragma unroll
                for (int r = 0; r < 16; ++r) {
                    float p = exp2f(fmaf(acc[tb][r], SCL2E, -mrow));
                    acc[tb][r] = p;
                    psum += p;
                }
            lsum += psum;

            // P -> bf16 fragments via cvt_pk + permlane32_swap:
            // lane (lo,hi) gets P[q=lo][t = 16*ks2 + 8*hi + j]
            bf16x8 pa[4];
            #pragma unroll
            for (int ks2 = 0; ks2 < 4; ++ks2) {
                const int tb = ks2 >> 1, rb = (ks2 & 1) * 8;
                int a0 = pkbf16(acc[tb][rb + 0], acc[tb][rb + 1]);
                int b0 = pkbf16(acc[tb][rb + 4], acc[tb][rb + 5]);
                int a1 = pkbf16(acc[tb][rb + 2], acc[tb][rb + 3]);
                int b1 = pkbf16(acc[tb][rb + 6], acc[tb][rb + 7]);
                int2v s1 = __builtin_amdgcn_permlane32_swap(a0, b0, false, false);
                int2v s2 = __builtin_amdgcn_permlane32_swap(a1, b1, false, false);
                union { int i[4]; bf16x8 v; } u;
                u.i[0] = s1[0]; u.i[1] = s2[0]; u.i[2] = s1[1]; u.i[3] = s2[1];
                pa[ks2] = u.v;
            }

            // PV transposed: O^T[d][q] += V^T[d][t] * P^T[t][q]
            #pragma unroll
            for (int ks2 = 0; ks2 < 4; ++ks2) {
                #pragma unroll
                for (int db = 0; db < 2; ++db) {
                    const int d = db * 32 + lo;
                    bf16x8 vb = *reinterpret_cast<const bf16x8*>(
                        vsb + d * 128 + (((2 * ks2 + hi) ^ (d & 7)) * 16));
                    oacc[db] = mfma32(vb, pa[ks2], oacc[db]);
                }
            }
        }
        __builtin_amdgcn_sched_barrier(0);
        __builtin_amdgcn_s_barrier();    // all reads of buf[cur] done before overwrite
        cur ^= 1;
    }

    // epilogue: lane-local normalize; store O[q=qg][d] with 8B-packed stores.
    // Lane's 16 values per db: d = db*32 + (r&3) + 8*(r>>2) + 4*hi.
    const int b = bh >> 4, h = bh & 15;
    float lsumt = lsum + __shfl_xor(lsum, 32);   // halves hold partial sums over t
    float inv = 1.0f / lsumt;
    __bf16* orow = Oa + ((size_t)(b * SS + qg)) * EDIM + h * HD;
    #pragma unroll
    for (int db = 0; db < 2; ++db) {
        #pragma unroll
        for (int g = 0; g < 4; ++g) {
            int d0 = db * 32 + g * 8 + 4 * hi;
            bf16x4 o4;
            o4.x = (__bf16)(oacc[db][g * 4 + 0] * inv);
            o4.y = (__bf16)(oacc[db][g * 4 + 1] * inv);
            o4.z = (__bf16)(oacc[db][g * 4 + 2] * inv);
            o4.w = (__bf16)(oacc[db][g * 4 + 3] * inv);
            *reinterpret_cast<bf16x4*>(orow + d0) = o4;
        }
    }
}

// ---------------- launch ----------------
extern "C" void kernel_launch(void* const* d_in, const int* in_sizes, int n_in,
                              void* d_out, int out_size, void* d_ws, size_t ws_size,
                              hipStream_t stream) {
    const float* x  = (const float*)d_in[0];
    const float* Wq = (const float*)d_in[1];
    const float* bq = (const float*)d_in[2];
    const float* Wk = (const float*)d_in[3];
    const float* bk = (const float*)d_in[4];
    const float* Wv = (const float*)d_in[5];
    const float* bv = (const float*)d_in[6];
    const float* Wo = (const float*)d_in[7];
    const float* bo = (const float*)d_in[8];

    char* ws = (char*)d_ws;
    const size_t SZ_XB  = (size_t)MROWS * EDIM * 2;       // 16 MB
    const size_t SZ_W   = (size_t)EDIM * EDIM * 2;        // 2 MB
    const size_t SZ_QKV = (size_t)BB * NH * SS * HD * 2;  // 16 MB

    __bf16* xb  = (__bf16*)(ws);
    __bf16* wqb = (__bf16*)(ws + SZ_XB);
    __bf16* wkb = (__bf16*)(ws + SZ_XB + SZ_W);
    __bf16* wvb = (__bf16*)(ws + SZ_XB + 2 * SZ_W);
    __bf16* wob = (__bf16*)(ws + SZ_XB + 3 * SZ_W);
    __bf16* Qb  = (__bf16*)(ws + SZ_XB + 4 * SZ_W);
    __bf16* Kb  = (__bf16*)(ws + SZ_XB + 4 * SZ_W + SZ_QKV);
    __bf16* Vtb = (__bf16*)(ws + SZ_XB + 4 * SZ_W + 2 * SZ_QKV);
    __bf16* Oab = (__bf16*)(ws + SZ_XB + 4 * SZ_W + 3 * SZ_QKV);

    cvt_kernel<<<MROWS * EDIM / 1024, 256, 0, stream>>>(x, xb, MROWS * EDIM);
    cvt_kernel<<<EDIM * EDIM / 1024, 256, 0, stream>>>(Wq, wqb, EDIM * EDIM);
    cvt_kernel<<<EDIM * EDIM / 1024, 256, 0, stream>>>(Wk, wkb, EDIM * EDIM);
    cvt_kernel<<<EDIM * EDIM / 1024, 256, 0, stream>>>(Wv, wvb, EDIM * EDIM);
    cvt_kernel<<<EDIM * EDIM / 1024, 256, 0, stream>>>(Wo, wob, EDIM * EDIM);

    dim3 ggrid(MROWS / 128, EDIM / 128);
    gemm_bt<<<ggrid, 256, 0, stream>>>(xb, wqb, bq, (void*)Qb, 0);
    gemm_bt<<<ggrid, 256, 0, stream>>>(xb, wkb, bk, (void*)Kb, 0);
    gemm_bt<<<ggrid, 256, 0, stream>>>(xb, wvb, bv, (void*)Vtb, 2);

    attn_kernel<<<dim3(BB * NH, 8), 512, 0, stream>>>(Qb, Kb, Vtb, Oab);

    gemm_bt<<<ggrid, 256, 0, stream>>>(Oab, wob, bo, d_out, 3);
}

// Round 15
// 215.611 us; speedup vs baseline: 1.3102x; 1.0383x over previous
//
#include <hip/hip_runtime.h>
#include <hip/hip_bf16.h>
#include <stdint.h>

// Problem constants
#define EDIM 1024
#define NH   16
#define HD   64
#define BB   4
#define SS   2048
#define MROWS (BB*SS)   // 8192

typedef __bf16 bf16x8 __attribute__((ext_vector_type(8)));
typedef __bf16 bf16x4 __attribute__((ext_vector_type(4)));
typedef float  f32x4  __attribute__((ext_vector_type(4)));
typedef float  f32x16 __attribute__((ext_vector_type(16)));
typedef int    int2v  __attribute__((ext_vector_type(2)));

__device__ __forceinline__ void async16(const void* g, void* lds) {
    __builtin_amdgcn_global_load_lds((__attribute__((address_space(1))) void*)(g),
                                     (__attribute__((address_space(3))) void*)(lds),
                                     16, 0, 0);
}

__device__ __forceinline__ f32x4 mfma16(bf16x8 a, bf16x8 b, f32x4 c) {
    return __builtin_amdgcn_mfma_f32_16x16x32_bf16(a, b, c, 0, 0, 0);
}
__device__ __forceinline__ f32x16 mfma32(bf16x8 a, bf16x8 b, f32x16 c) {
    return __builtin_amdgcn_mfma_f32_32x32x16_bf16(a, b, c, 0, 0, 0);
}

// pack two f32 -> one u32 of 2 bf16 (compiler emits v_cvt_pk_bf16_f32)
__device__ __forceinline__ int pkbf16(float a, float b) {
    union { __bf16 h[2]; int i; } u;
    u.h[0] = (__bf16)a; u.h[1] = (__bf16)b;
    return u.i;
}

// ---------------- fp32 -> bf16 conversion (vectorized) ----------------
__global__ __launch_bounds__(256) void cvt_kernel(const float* __restrict__ s,
                                                  __bf16* __restrict__ d, int n) {
    int i = (blockIdx.x * 256 + threadIdx.x) * 4;
    if (i < n) {
        float4 v = *reinterpret_cast<const float4*>(s + i);
        bf16x4 o;
        o.x = (__bf16)v.x; o.y = (__bf16)v.y; o.z = (__bf16)v.z; o.w = (__bf16)v.w;
        *reinterpret_cast<bf16x4*>(d + i) = o;
    }
}

// ---------------- Fused QKV GEMM: N=3072 (W rows 0..1023=Q, ..2047=K, ..3071=V) --
// A: [8192,1024] bf16. W: [3072,1024] bf16 (contiguous wq|wk|wv). Outputs:
// Q,K -> [B,H,S,D] bf16;  V -> [B,H,D,S] bf16 (transposed).
__global__ __launch_bounds__(256) void gemm_qkv(const __bf16* __restrict__ A,
                                                const __bf16* __restrict__ W,
                                                const float* __restrict__ bq,
                                                const float* __restrict__ bk,
                                                const float* __restrict__ bv,
                                                __bf16* __restrict__ Qb,
                                                __bf16* __restrict__ Kb,
                                                __bf16* __restrict__ Vtb) {
    __shared__ char As[128 * 64];
    __shared__ char Bs[128 * 64];

    const int tid = threadIdx.x;
    const int w = tid >> 6, l = tid & 63;
    const int bm = blockIdx.x * 128, bn = blockIdx.y * 128;
    const int wm = (w >> 1) * 64, wn = (w & 1) * 64;

    f32x4 acc[4][4] = {};
    const int lrow = l & 15;
    const int lslot = l >> 4;

    for (int kt = 0; kt < EDIM / 32; ++kt) {
        const int k0 = kt * 32;
        #pragma unroll
        for (int i = 0; i < 2; ++i) {
            int c = i * 256 + tid;
            int row = c >> 2, cb = c & 3;
            int gk = k0 + ((cb ^ (row & 3)) << 3);
            async16(A + (size_t)(bm + row) * EDIM + gk, As + (i * 256 + w * 64) * 16);
            async16(W + (size_t)(bn + row) * EDIM + gk, Bs + (i * 256 + w * 64) * 16);
        }
        __syncthreads();

        bf16x8 af[4], bfr[4];
        #pragma unroll
        for (int mf = 0; mf < 4; ++mf) {
            int row = wm + mf * 16 + lrow;
            af[mf] = *reinterpret_cast<const bf16x8*>(As + row * 64 + ((lslot ^ (row & 3)) << 4));
        }
        #pragma unroll
        for (int nf = 0; nf < 4; ++nf) {
            int row = wn + nf * 16 + lrow;
            bfr[nf] = *reinterpret_cast<const bf16x8*>(Bs + row * 64 + ((lslot ^ (row & 3)) << 4));
        }
        #pragma unroll
        for (int mf = 0; mf < 4; ++mf)
            #pragma unroll
            for (int nf = 0; nf < 4; ++nf)
                acc[mf][nf] = mfma16(af[mf], bfr[nf], acc[mf][nf]);
        __syncthreads();
    }

    const int mat = bn >> 10;                       // 0=Q, 1=K, 2=V (block-uniform)
    const float* bias = (mat == 0) ? bq : (mat == 1) ? bk : bv;
    __bf16* qk = (mat == 0) ? Qb : Kb;

    #pragma unroll
    for (int nf = 0; nf < 4; ++nf) {
        int ng = bn + wn + nf * 16 + lrow;
        int nn = ng & 1023;
        int h = nn >> 6, d = nn & 63;
        float bval = bias[nn];
        #pragma unroll
        for (int mf = 0; mf < 4; ++mf) {
            #pragma unroll
            for (int r = 0; r < 4; ++r) {
                int mg = bm + wm + mf * 16 + (l >> 4) * 4 + r;
                float v = acc[mf][nf][r] + bval;
                int b = mg >> 11, s = mg & 2047;
                if (mat == 2)
                    Vtb[((size_t)(b * NH + h) * HD + d) * SS + s] = (__bf16)v;
                else
                    qk[((size_t)(b * NH + h) * SS + s) * HD + d] = (__bf16)v;
            }
        }
    }
}

// ---------------- Output GEMM: C[m][n] = sum_k A[m][k]*W[n][k] + bias[n], fp32 out
__global__ __launch_bounds__(256) void gemm_out(const __bf16* __restrict__ A,
                                                const __bf16* __restrict__ W,
                                                const float* __restrict__ bias,
                                                float* __restrict__ dst) {
    __shared__ char As[128 * 64];
    __shared__ char Bs[128 * 64];

    const int tid = threadIdx.x;
    const int w = tid >> 6, l = tid & 63;
    const int bm = blockIdx.x * 128, bn = blockIdx.y * 128;
    const int wm = (w >> 1) * 64, wn = (w & 1) * 64;

    f32x4 acc[4][4] = {};
    const int lrow = l & 15;
    const int lslot = l >> 4;

    for (int kt = 0; kt < EDIM / 32; ++kt) {
        const int k0 = kt * 32;
        #pragma unroll
        for (int i = 0; i < 2; ++i) {
            int c = i * 256 + tid;
            int row = c >> 2, cb = c & 3;
            int gk = k0 + ((cb ^ (row & 3)) << 3);
            async16(A + (size_t)(bm + row) * EDIM + gk, As + (i * 256 + w * 64) * 16);
            async16(W + (size_t)(bn + row) * EDIM + gk, Bs + (i * 256 + w * 64) * 16);
        }
        __syncthreads();

        bf16x8 af[4], bfr[4];
        #pragma unroll
        for (int mf = 0; mf < 4; ++mf) {
            int row = wm + mf * 16 + lrow;
            af[mf] = *reinterpret_cast<const bf16x8*>(As + row * 64 + ((lslot ^ (row & 3)) << 4));
        }
        #pragma unroll
        for (int nf = 0; nf < 4; ++nf) {
            int row = wn + nf * 16 + lrow;
            bfr[nf] = *reinterpret_cast<const bf16x8*>(Bs + row * 64 + ((lslot ^ (row & 3)) << 4));
        }
        #pragma unroll
        for (int mf = 0; mf < 4; ++mf)
            #pragma unroll
            for (int nf = 0; nf < 4; ++nf)
                acc[mf][nf] = mfma16(af[mf], bfr[nf], acc[mf][nf]);
        __syncthreads();
    }

    #pragma unroll
    for (int nf = 0; nf < 4; ++nf) {
        int ng = bn + wn + nf * 16 + lrow;
        float bval = bias[ng];
        #pragma unroll
        for (int mf = 0; mf < 4; ++mf) {
            #pragma unroll
            for (int r = 0; r < 4; ++r) {
                int mg = bm + wm + mf * 16 + (l >> 4) * 4 + r;
                dst[(size_t)mg * EDIM + ng] = acc[mf][nf][r] + bval;
            }
        }
    }
}

// ---------------- Flash attention (causal, swapped-QK^T, in-register softmax,
//                  2-tile-unrolled double-buffer, literal LDS bases, setprio) ----
#define SCL2E 0.18033688f   /* 0.125 * log2(e) */

__global__ __launch_bounds__(512) void attn_kernel(const __bf16* __restrict__ Q,
                                                   const __bf16* __restrict__ K,
                                                   const __bf16* __restrict__ Vt,
                                                   __bf16* __restrict__ Oa) {
    __shared__ char ks0[64 * 128], vs0[64 * 128];
    __shared__ char ks1[64 * 128], vs1[64 * 128];

    const int bh = blockIdx.x;          // 0..63
    const int qt = 7 - blockIdx.y;      // 0..7, longest first
    const int tid = threadIdx.x;
    const int w = tid >> 6;             // warp 0..7
    const int l = tid & 63;
    const int lo = l & 31;
    const int hi = l >> 5;

    const __bf16* Qp = Q + (size_t)bh * (SS * HD);
    const __bf16* Kp = K + (size_t)bh * (SS * HD);
    const __bf16* Vp = Vt + (size_t)bh * (HD * SS);

    // Q B-fragments: col=q=lo, k = d = kc*16 + hi*8 + j
    const int qg = qt * 256 + w * 32 + lo;
    bf16x8 qf[4];
    #pragma unroll
    for (int kc = 0; kc < 4; ++kc)
        qf[kc] = *reinterpret_cast<const bf16x8*>(Qp + (size_t)qg * HD + kc * 16 + hi * 8);

    // staging: one 16B chunk per thread per matrix
    const int rowS = tid >> 3, cbS = tid & 7;
    const int gsS = (cbS ^ (rowS & 7)) << 3;
    const int wb = w * 1024;
    const __bf16* kp = Kp + (size_t)rowS * HD + gsS;
    const __bf16* vp = Vp + (size_t)rowS * SS + gsS;

    f32x16 oacc[2] = {};                 // O^T[d][q = lo]
    float mrow = -1e30f;
    float lsum = 0.f;

    const int qwhi = qt * 256 + w * 32 + 31;
    const int ntiles = 4 * qt + 4;       // always even

    auto compute = [&](const char* ksb, const char* vsb, int kv0) {
        // QK^T: S[t][q], acc[tb]: t = tb*32 + crow(r) + 4*hi, q = lo
        f32x16 acc[2] = {};
        __builtin_amdgcn_s_setprio(1);
        #pragma unroll
        for (int tb = 0; tb < 2; ++tb) {
            const int t = tb * 32 + lo;
            const char* krow = ksb + t * 128;
            const int tx = (t & 7);
            #pragma unroll
            for (int kc = 0; kc < 4; ++kc) {
                bf16x8 kf = *reinterpret_cast<const bf16x8*>(krow + ((2 * kc + hi) ^ tx) * 16);
                acc[tb] = mfma32(kf, qf[kc], acc[tb]);
            }
        }
        __builtin_amdgcn_s_setprio(0);

        // causal mask (raw scores), only near the diagonal
        if (kv0 + 63 > qg - lo) {   // kv0+63 > qwlo (warp-uniform)
            #pragma unroll
            for (int tb = 0; tb < 2; ++tb)
                #pragma unroll
                for (int r = 0; r < 16; ++r) {
                    int t = kv0 + tb * 32 + ((r & 3) + 8 * (r >> 2)) + 4 * hi;
                    if (t > qg) acc[tb][r] = -1e30f;
                }
        }

        // in-register online softmax (scalar m/lsum per lane; row = q = lo)
        float mx = acc[0][0];
        #pragma unroll
        for (int r = 1; r < 16; ++r) mx = fmaxf(mx, acc[0][r]);
        #pragma unroll
        for (int r = 0; r < 16; ++r) mx = fmaxf(mx, acc[1][r]);
        mx = fmaxf(mx, __shfl_xor(mx, 32));
        float mxs = mx * SCL2E;
        // T13 defer-max
        if (!__all(mxs <= mrow + 8.0f)) {
            float mnew = fmaxf(mrow, mxs);
            float alpha = exp2f(mrow - mnew);
            mrow = mnew;
            lsum *= alpha;
            oacc[0] *= alpha;
            oacc[1] *= alpha;
        }
        float psum = 0.f;
        #pragma unroll
        for (int tb = 0; tb < 2; ++tb)
            #pragma unroll
            for (int r = 0; r < 16; ++r) {
                float p = exp2f(fmaf(acc[tb][r], SCL2E, -mrow));
                acc[tb][r] = p;
                psum += p;
            }
        lsum += psum;

        // P -> bf16 fragments via cvt_pk + permlane32_swap
        bf16x8 pa[4];
        #pragma unroll
        for (int ks2 = 0; ks2 < 4; ++ks2) {
            const int tb = ks2 >> 1, rb = (ks2 & 1) * 8;
            int a0 = pkbf16(acc[tb][rb + 0], acc[tb][rb + 1]);
            int b0 = pkbf16(acc[tb][rb + 4], acc[tb][rb + 5]);
            int a1 = pkbf16(acc[tb][rb + 2], acc[tb][rb + 3]);
            int b1 = pkbf16(acc[tb][rb + 6], acc[tb][rb + 7]);
            int2v s1 = __builtin_amdgcn_permlane32_swap(a0, b0, false, false);
            int2v s2 = __builtin_amdgcn_permlane32_swap(a1, b1, false, false);
            union { int i[4]; bf16x8 v; } u;
            u.i[0] = s1[0]; u.i[1] = s2[0]; u.i[2] = s1[1]; u.i[3] = s2[1];
            pa[ks2] = u.v;
        }

        // PV transposed: O^T[d][q] += V^T[d][t] * P^T[t][q]
        __builtin_amdgcn_s_setprio(1);
        #pragma unroll
        for (int ks2 = 0; ks2 < 4; ++ks2) {
            #pragma unroll
            for (int db = 0; db < 2; ++db) {
                const int d = db * 32 + lo;
                bf16x8 vb = *reinterpret_cast<const bf16x8*>(
                    vsb + d * 128 + (((2 * ks2 + hi) ^ (d & 7)) * 16));
                oacc[db] = mfma32(vb, pa[ks2], oacc[db]);
            }
        }
        __builtin_amdgcn_s_setprio(0);
    };

    // prologue: stage tile 0 into buffer 0
    async16(kp, ks0 + wb);
    async16(vp, vs0 + wb);
    kp += 64 * HD; vp += 64;

    for (int kt = 0; kt < ntiles; kt += 2) {
        // ---- phase A: compute tile kt (buf0); prefetch kt+1 -> buf1
        async16(kp, ks1 + wb);
        async16(vp, vs1 + wb);
        kp += 64 * HD; vp += 64;
        asm volatile("s_waitcnt vmcnt(2)" ::: "memory");   // tile kt landed
        __builtin_amdgcn_s_barrier();
        __builtin_amdgcn_sched_barrier(0);
        if (kt * 64 <= qwhi) compute(ks0, vs0, kt * 64);
        __builtin_amdgcn_sched_barrier(0);
        __builtin_amdgcn_s_barrier();                      // buf0 reads done

        // ---- phase B: compute tile kt+1 (buf1); prefetch kt+2 -> buf0
        if (kt + 2 < ntiles) {
            async16(kp, ks0 + wb);
            async16(vp, vs0 + wb);
            kp += 64 * HD; vp += 64;
            asm volatile("s_waitcnt vmcnt(2)" ::: "memory");
        } else {
            asm volatile("s_waitcnt vmcnt(0)" ::: "memory");
        }
        __builtin_amdgcn_s_barrier();
        __builtin_amdgcn_sched_barrier(0);
        if ((kt + 1) * 64 <= qwhi) compute(ks1, vs1, (kt + 1) * 64);
        __builtin_amdgcn_sched_barrier(0);
        __builtin_amdgcn_s_barrier();                      // buf1 reads done
    }

    // epilogue: lane-local normalize; store O[q=qg][d] with 8B-packed stores.
    const int b = bh >> 4, h = bh & 15;
    float lsumt = lsum + __shfl_xor(lsum, 32);
    float inv = 1.0f / lsumt;
    __bf16* orow = Oa + ((size_t)(b * SS + qg)) * EDIM + h * HD;
    #pragma unroll
    for (int db = 0; db < 2; ++db) {
        #pragma unroll
        for (int g = 0; g < 4; ++g) {
            int d0 = db * 32 + g * 8 + 4 * hi;
            bf16x4 o4;
            o4.x = (__bf16)(oacc[db][g * 4 + 0] * inv);
            o4.y = (__bf16)(oacc[db][g * 4 + 1] * inv);
            o4.z = (__bf16)(oacc[db][g * 4 + 2] * inv);
            o4.w = (__bf16)(oacc[db][g * 4 + 3] * inv);
            *reinterpret_cast<bf16x4*>(orow + d0) = o4;
        }
    }
}

// ---------------- launch ----------------
extern "C" void kernel_launch(void* const* d_in, const int* in_sizes, int n_in,
                              void* d_out, int out_size, void* d_ws, size_t ws_size,
                              hipStream_t stream) {
    const float* x  = (const float*)d_in[0];
    const float* Wq = (const float*)d_in[1];
    const float* bq = (const float*)d_in[2];
    const float* Wk = (const float*)d_in[3];
    const float* bk = (const float*)d_in[4];
    const float* Wv = (const float*)d_in[5];
    const float* bv = (const float*)d_in[6];
    const float* Wo = (const float*)d_in[7];
    const float* bo = (const float*)d_in[8];

    char* ws = (char*)d_ws;
    const size_t SZ_XB  = (size_t)MROWS * EDIM * 2;       // 16 MB
    const size_t SZ_W   = (size_t)EDIM * EDIM * 2;        // 2 MB
    const size_t SZ_QKV = (size_t)BB * NH * SS * HD * 2;  // 16 MB

    __bf16* xb  = (__bf16*)(ws);
    __bf16* wqb = (__bf16*)(ws + SZ_XB);                  // wq|wk|wv contiguous
    __bf16* wkb = (__bf16*)(ws + SZ_XB + SZ_W);
    __bf16* wvb = (__bf16*)(ws + SZ_XB + 2 * SZ_W);
    __bf16* wob = (__bf16*)(ws + SZ_XB + 3 * SZ_W);
    __bf16* Qb  = (__bf16*)(ws + SZ_XB + 4 * SZ_W);
    __bf16* Kb  = (__bf16*)(ws + SZ_XB + 4 * SZ_W + SZ_QKV);
    __bf16* Vtb = (__bf16*)(ws + SZ_XB + 4 * SZ_W + 2 * SZ_QKV);
    __bf16* Oab = (__bf16*)(ws + SZ_XB + 4 * SZ_W + 3 * SZ_QKV);

    cvt_kernel<<<MROWS * EDIM / 1024, 256, 0, stream>>>(x, xb, MROWS * EDIM);
    cvt_kernel<<<EDIM * EDIM / 1024, 256, 0, stream>>>(Wq, wqb, EDIM * EDIM);
    cvt_kernel<<<EDIM * EDIM / 1024, 256, 0, stream>>>(Wk, wkb, EDIM * EDIM);
    cvt_kernel<<<EDIM * EDIM / 1024, 256, 0, stream>>>(Wv, wvb, EDIM * EDIM);
    cvt_kernel<<<EDIM * EDIM / 1024, 256, 0, stream>>>(Wo, wob, EDIM * EDIM);

    // fused QKV projection: N = 3072
    gemm_qkv<<<dim3(MROWS / 128, 3 * EDIM / 128), 256, 0, stream>>>(
        xb, wqb, bq, bk, bv, Qb, Kb, Vtb);

    attn_kernel<<<dim3(BB * NH, 8), 512, 0, stream>>>(Qb, Kb, Vtb, Oab);

    gemm_out<<<dim3(MROWS / 128, EDIM / 128), 256, 0, stream>>>(
        Oab, wob, bo, (float*)d_out);
}